// Round 1
// 1338.980 us; speedup vs baseline: 1.2132x; 1.2132x over previous
//
#include <hip/hip_runtime.h>

typedef unsigned short u16;
typedef unsigned int u32;
typedef __attribute__((ext_vector_type(8))) __bf16 bf16x8;
typedef __attribute__((ext_vector_type(4))) float floatx4;

#define TB 24
#define NN 2048
#define QC 192

__device__ __forceinline__ float b2f(u16 v) { return __uint_as_float(((u32)v) << 16); }
__device__ __forceinline__ u16 f2bu(float f) {
  u32 u = __float_as_uint(f);
  u32 r = (u + 0x7fffu + ((u >> 16) & 1u)) >> 16;
  return (u16)r;
}
__device__ __forceinline__ u32 packpair(float a, float b) {
  return (u32)f2bu(a) | ((u32)f2bu(b) << 16);
}
__device__ __forceinline__ void unpack8(uint4 v, float* f) {
  f[0] = __uint_as_float(v.x << 16); f[1] = __uint_as_float(v.x & 0xffff0000u);
  f[2] = __uint_as_float(v.y << 16); f[3] = __uint_as_float(v.y & 0xffff0000u);
  f[4] = __uint_as_float(v.z << 16); f[5] = __uint_as_float(v.z & 0xffff0000u);
  f[6] = __uint_as_float(v.w << 16); f[7] = __uint_as_float(v.w & 0xffff0000u);
}
__device__ __forceinline__ float wredsum(float v) {
#pragma unroll
  for (int m = 32; m > 0; m >>= 1) v += __shfl_xor(v, m, 64);
  return v;
}
// reduce across the 16-lane group (lanes sharing lq) -- xor masks 1,2,4,8
__device__ __forceinline__ float red16(float v) {
#pragma unroll
  for (int m = 8; m > 0; m >>= 1) v += __shfl_xor(v, m, 64);
  return v;
}

// all 8 weight matrices fp32 -> bf16 in one dispatch (65536 elements total)
__global__ __launch_bounds__(256) void cast_weights(
    const float* __restrict__ q0, const float* __restrict__ q1,
    const float* __restrict__ o0, const float* __restrict__ o1,
    const float* __restrict__ p0, const float* __restrict__ p1,
    const float* __restrict__ f1, const float* __restrict__ f2,
    u16* __restrict__ dst) {
  int i = blockIdx.x * 256 + threadIdx.x;
  float v;
  if (i < 12288) v = q0[i];
  else if (i < 24576) v = q1[i - 12288];
  else if (i < 32768) v = o0[i - 24576];
  else if (i < 40960) v = o1[i - 32768];
  else if (i < 45056) v = p0[i - 40960];
  else if (i < 49152) v = p1[i - 45056];
  else if (i < 57344) v = f1[i - 49152];
  else v = f2[i - 57344];
  dst[i] = f2bu(v);
}

// bulk fp32 -> bf16 cast, 8 elements/thread (for phi)
__global__ __launch_bounds__(256) void cast_bulk(const float* __restrict__ src,
                                                 u16* __restrict__ dst) {
  long i = ((long)blockIdx.x * 256 + threadIdx.x) * 8;
  float4 a = *(const float4*)(src + i);
  float4 b = *(const float4*)(src + i + 4);
  uint4 o = uint4{packpair(a.x, a.y), packpair(a.z, a.w),
                  packpair(b.x, b.y), packpair(b.z, b.w)};
  *(uint4*)(dst + i) = o;
}

// PT[s][i][j] = diag[s][j] * phi_inv[s][j][i]  (fp32 in, bf16 out); s = blockIdx.z
__global__ __launch_bounds__(256) void prep_pt(const float* __restrict__ phi_inv,
                                               const float* __restrict__ diag,
                                               u16* __restrict__ PT) {
  const int s = blockIdx.z;
  const float* phi_inv_s = phi_inv + (long)s * 4194304;
  const float* diag_s = diag + (long)s * 2048;
  u16* PTs = PT + (long)s * 4194304;
  const long i0 = (long)blockIdx.x * 64, j0 = (long)blockIdx.y * 64;
  __shared__ float tile[64][65];
  for (int t = threadIdx.x; t < 512; t += 256) {
    int r = t >> 3, c8 = (t & 7) << 3;
    float dv = diag_s[j0 + r];
    const float* sp = phi_inv_s + (j0 + r) * 2048 + i0 + c8;
    float4 p = *(const float4*)sp;
    float4 q = *(const float4*)(sp + 4);
    tile[r][c8 + 0] = p.x * dv; tile[r][c8 + 1] = p.y * dv;
    tile[r][c8 + 2] = p.z * dv; tile[r][c8 + 3] = p.w * dv;
    tile[r][c8 + 4] = q.x * dv; tile[r][c8 + 5] = q.y * dv;
    tile[r][c8 + 6] = q.z * dv; tile[r][c8 + 7] = q.w * dv;
  }
  __syncthreads();
  for (int t = threadIdx.x; t < 512; t += 256) {
    int r = t >> 3, c8 = (t & 7) << 3;
    uint4 o;
    o.x = packpair(tile[c8 + 0][r], tile[c8 + 1][r]);
    o.y = packpair(tile[c8 + 2][r], tile[c8 + 3][r]);
    o.z = packpair(tile[c8 + 4][r], tile[c8 + 5][r]);
    o.w = packpair(tile[c8 + 6][r], tile[c8 + 7][r]);
    *(uint4*)(PTs + (i0 + r) * 2048 + j0 + c8) = o;
  }
}

// XT[bt][c][j] = x[bt][j][c]  (fp32 in, bf16 out); optional row-major bf16 copy XB
__global__ __launch_bounds__(256) void prep_xt(const float* __restrict__ x,
                                               u16* __restrict__ XT,
                                               u16* __restrict__ XB) {
  const int bt = blockIdx.y;
  const long j0 = (long)blockIdx.x * 64;
  __shared__ float tile[64][65];
  const float* src = x + (long)bt * NN * 64;
  for (int t = threadIdx.x; t < 512; t += 256) {
    int r = t >> 3, c8 = (t & 7) << 3;
    const float* sp = src + (j0 + r) * 64 + c8;
    float4 p = *(const float4*)sp;
    float4 q = *(const float4*)(sp + 4);
    tile[r][c8 + 0] = p.x; tile[r][c8 + 1] = p.y;
    tile[r][c8 + 2] = p.z; tile[r][c8 + 3] = p.w;
    tile[r][c8 + 4] = q.x; tile[r][c8 + 5] = q.y;
    tile[r][c8 + 6] = q.z; tile[r][c8 + 7] = q.w;
    if (XB) {
      uint4 o = uint4{packpair(p.x, p.y), packpair(p.z, p.w),
                      packpair(q.x, q.y), packpair(q.z, q.w)};
      *(uint4*)(XB + (long)bt * 131072 + (j0 + r) * 64 + c8) = o;
    }
  }
  __syncthreads();
  u16* dst = XT + (long)bt * 64 * NN;
  for (int t = threadIdx.x; t < 512; t += 256) {
    int r = t >> 3, c8 = (t & 7) << 3;
    uint4 o;
    o.x = packpair(tile[c8 + 0][r], tile[c8 + 1][r]);
    o.y = packpair(tile[c8 + 2][r], tile[c8 + 3][r]);
    o.z = packpair(tile[c8 + 4][r], tile[c8 + 5][r]);
    o.w = packpair(tile[c8 + 6][r], tile[c8 + 7][r]);
    *(uint4*)(dst + (long)r * 2048 + j0 + c8) = o;
  }
}

// m97-style 128x128x(BK=64) GEMM, bf16 A/Bt, fp32 accum, global_load_lds staging
// with XOR chunk swizzle + XCD-aware block swizzle (nwg_xy % 8 == 0 required).
// MODE 0: C bf16 row-major (ldc). MODE 1: fp32 scatter C[col>>6][row][col&63].
// MODE 2: split-K over blockIdx.z (A/B offset z*aseg/bseg), fp32 partial at
//         C + z*4194304. MODE 3: bf16 scatter C[col>>6][row][col&63].
template <int MODE>
__global__ __launch_bounds__(256) void gemm128(
    const u16* __restrict__ A, const u16* __restrict__ Bt, void* __restrict__ C,
    int K, int lda, int ldb, int ldc, int nseg, long aseg, long bseg) {
  __shared__ __align__(16) u16 As[128 * 64];
  __shared__ __align__(16) u16 Bs[128 * 64];
  const int tid = threadIdx.x;
  const int wave = tid >> 6, lane = tid & 63;
  const int l15 = lane & 15, lq = lane >> 4;
  const int wr = wave >> 1, wc = wave & 1;
  // XCD-aware swizzle over the xy plane (id%8 == XCD since nwg_xy%8==0)
  const int nbx = gridDim.x;
  const int nwg = nbx * gridDim.y;
  int id = blockIdx.x + nbx * blockIdx.y;
  id = (id & 7) * (nwg >> 3) + (id >> 3);
  const long m0 = (long)(id % nbx) * 128;
  const long n0 = (long)(id / nbx) * 128;
  const long zo = (MODE == 2) ? (long)blockIdx.z : 0;
  const int rl = lane >> 3;               // row within an 8-row load group
  const int csw = (lane & 7) ^ rl;        // XOR-swizzled source chunk (16B units)
  floatx4 acc[4][4];
#pragma unroll
  for (int a = 0; a < 4; a++)
#pragma unroll
    for (int b = 0; b < 4; b++) acc[a][b] = floatx4{0.f, 0.f, 0.f, 0.f};
  for (int s = 0; s < nseg; s++) {
    const u16* Ab = A + (s + zo) * aseg;
    const u16* Bb = Bt + (s + zo) * bseg;
    for (int k0 = 0; k0 < K; k0 += 64) {
      __syncthreads();
#pragma unroll
      for (int la = 0; la < 4; la++) {
        const int ldx = wave * 4 + la;      // 0..15: 8-row group index
        const int rowt = ldx * 8 + rl;      // tile row 0..127
        const u16* ga = Ab + (m0 + rowt) * (long)lda + k0 + csw * 8;
        const u16* gb = Bb + (n0 + rowt) * (long)ldb + k0 + csw * 8;
        __builtin_amdgcn_global_load_lds(
            (const __attribute__((address_space(1))) void*)ga,
            (__attribute__((address_space(3))) void*)(As + ldx * 512), 16, 0, 0);
        __builtin_amdgcn_global_load_lds(
            (const __attribute__((address_space(1))) void*)gb,
            (__attribute__((address_space(3))) void*)(Bs + ldx * 512), 16, 0, 0);
      }
      __syncthreads();
#pragma unroll
      for (int ks = 0; ks < 2; ks++) {
        bf16x8 af[4], bf[4];
        const int cp = ((ks * 4 + lq) ^ (l15 & 7)) * 8;  // swizzled chunk pos
#pragma unroll
        for (int t = 0; t < 4; t++) {
          af[t] = *(const bf16x8*)(As + (wr * 64 + t * 16 + l15) * 64 + cp);
          bf[t] = *(const bf16x8*)(Bs + (wc * 64 + t * 16 + l15) * 64 + cp);
        }
#pragma unroll
        for (int ti = 0; ti < 4; ti++)
#pragma unroll
          for (int tj = 0; tj < 4; tj++)
            acc[ti][tj] = __builtin_amdgcn_mfma_f32_16x16x32_bf16(
                af[ti], bf[tj], acc[ti][tj], 0, 0, 0);
      }
    }
  }
#pragma unroll
  for (int ti = 0; ti < 4; ti++) {
#pragma unroll
    for (int tj = 0; tj < 4; tj++) {
#pragma unroll
      for (int i = 0; i < 4; i++) {
        const long row = m0 + wr * 64 + ti * 16 + lq * 4 + i;
        const long col = n0 + wc * 64 + tj * 16 + l15;
        if (MODE == 0) {
          ((u16*)C)[row * ldc + col] = f2bu(acc[ti][tj][i]);
        } else if (MODE == 1) {
          ((float*)C)[(col >> 6) * 131072L + row * 64 + (col & 63)] = acc[ti][tj][i];
        } else if (MODE == 2) {
          ((float*)C)[zo * 4194304L + row * (long)ldc + col] = acc[ti][tj][i];
        } else {
          ((u16*)C)[(col >> 6) * 131072L + row * 64 + (col & 63)] =
              f2bu(acc[ti][tj][i]);
        }
      }
    }
  }
}

// Ms = bf16( sum_z MsP[z] ), 4 partials of 2048x2048 fp32
__global__ __launch_bounds__(256) void reduce_ms(const float* __restrict__ P,
                                                 u16* __restrict__ M) {
  long i = ((long)blockIdx.x * 256 + threadIdx.x) * 8;
  float s[8];
  {
    float4 a = *(const float4*)(P + i);
    float4 b = *(const float4*)(P + i + 4);
    s[0] = a.x; s[1] = a.y; s[2] = a.z; s[3] = a.w;
    s[4] = b.x; s[5] = b.y; s[6] = b.z; s[7] = b.w;
  }
#pragma unroll
  for (int z = 1; z < 4; z++) {
    const float* p = P + (long)z * 4194304L + i;
    float4 a = *(const float4*)p;
    float4 b = *(const float4*)(p + 4);
    s[0] += a.x; s[1] += a.y; s[2] += a.z; s[3] += a.w;
    s[4] += b.x; s[5] += b.y; s[6] += b.z; s[7] += b.w;
  }
  uint4 o = uint4{packpair(s[0], s[1]), packpair(s[2], s[3]),
                  packpair(s[4], s[5]), packpair(s[6], s[7])};
  *(uint4*)(M + i) = o;
}

// C[M,N] (+)= sum_seg A[M,K] @ Bt[N,K]^T. A fp32/bf16 (AF32), C fp32/bf16 (CF32).
// (fallback path for small-ws tiers only)
template <bool AF32, bool CF32>
__global__ __launch_bounds__(256) void gemm_bt(
    const void* __restrict__ A, const u16* __restrict__ Bt, void* __restrict__ C,
    int K, int lda, int ldb, int ldc, int nseg, long aseg, long bseg,
    long bbstride, long cbstride, int accum) {
  __shared__ __align__(16) u16 Asm[64][72];
  __shared__ __align__(16) u16 Bsm[64][72];
  const int tid = threadIdx.x;
  const int wave = tid >> 6, lane = tid & 63;
  const int l15 = lane & 15, lq = lane >> 4;
  const long m0 = (long)blockIdx.x * 64;
  const long n0 = (long)blockIdx.y * 64;
  const long bz = blockIdx.z;
  const int srow = tid >> 3;
  const int scol = (tid & 7) << 3;
  floatx4 acc[4];
#pragma unroll
  for (int t = 0; t < 4; t++) acc[t] = floatx4{0.f, 0.f, 0.f, 0.f};
  for (int s = 0; s < nseg; s++) {
    const u16* Bb = Bt + s * bseg + bz * bbstride;
    for (int k0 = 0; k0 < K; k0 += 64) {
      __syncthreads();
      uint4 a0, a1;
      if (AF32) {
        const float* Af = (const float*)A + s * aseg;
        const float* p0 = Af + (m0 + srow) * lda + k0 + scol;
        const float* p1 = Af + (m0 + srow + 32) * lda + k0 + scol;
        float4 x0 = *(const float4*)p0, x1 = *(const float4*)(p0 + 4);
        float4 y0 = *(const float4*)p1, y1 = *(const float4*)(p1 + 4);
        a0 = uint4{packpair(x0.x, x0.y), packpair(x0.z, x0.w),
                   packpair(x1.x, x1.y), packpair(x1.z, x1.w)};
        a1 = uint4{packpair(y0.x, y0.y), packpair(y0.z, y0.w),
                   packpair(y1.x, y1.y), packpair(y1.z, y1.w)};
      } else {
        const u16* Ab = (const u16*)A + s * aseg;
        a0 = *(const uint4*)(Ab + (m0 + srow) * lda + k0 + scol);
        a1 = *(const uint4*)(Ab + (m0 + srow + 32) * lda + k0 + scol);
      }
      uint4 b0 = *(const uint4*)(Bb + (n0 + srow) * ldb + k0 + scol);
      uint4 b1 = *(const uint4*)(Bb + (n0 + srow + 32) * ldb + k0 + scol);
      *(uint4*)(&Asm[srow][scol]) = a0;
      *(uint4*)(&Asm[srow + 32][scol]) = a1;
      *(uint4*)(&Bsm[srow][scol]) = b0;
      *(uint4*)(&Bsm[srow + 32][scol]) = b1;
      __syncthreads();
#pragma unroll
      for (int ks = 0; ks < 2; ks++) {
        bf16x8 af = *(const bf16x8*)(&Asm[wave * 16 + l15][ks * 32 + lq * 8]);
#pragma unroll
        for (int t = 0; t < 4; t++) {
          bf16x8 bfr = *(const bf16x8*)(&Bsm[t * 16 + l15][ks * 32 + lq * 8]);
          acc[t] = __builtin_amdgcn_mfma_f32_16x16x32_bf16(af, bfr, acc[t], 0, 0, 0);
        }
      }
    }
  }
#pragma unroll
  for (int t = 0; t < 4; t++) {
#pragma unroll
    for (int i = 0; i < 4; i++) {
      long off = (m0 + wave * 16 + lq * 4 + i) * ldc + n0 + t * 16 + l15;
      float v = acc[t][i];
      if (CF32) {
        float* Cb = (float*)C + bz * cbstride;
        if (accum) v += Cb[off];
        Cb[off] = v;
      } else {
        u16* Cb = (u16*)C + bz * cbstride;
        if (accum) v += b2f(Cb[off]);
        Cb[off] = f2bu(v);
      }
    }
  }
}

// Out[m, 0:NOUT (stride LDO)] = In[m, 0:K (stride LDA)] @ W[NOUT,K]^T (+bias, relu)
template <int K, int LDA, int NOUT, int LDO, bool BIAS, bool RELU, bool AF32, bool OF32>
__global__ __launch_bounds__(256) void skinny_gemm(const void* __restrict__ In,
                                                   const u16* __restrict__ W,
                                                   const float* __restrict__ Bv,
                                                   void* __restrict__ Out) {
  constexpr int NT = NOUT / 16;
  const int lane = threadIdx.x & 63;
  const int wave = threadIdx.x >> 6;
  const int l15 = lane & 15, lq = lane >> 4;
  const long m0 = ((long)blockIdx.x * 4 + wave) * 16;
  floatx4 acc[NT];
#pragma unroll
  for (int t = 0; t < NT; t++) acc[t] = floatx4{0.f, 0.f, 0.f, 0.f};
#pragma unroll
  for (int k0 = 0; k0 < K; k0 += 32) {
    bf16x8 af;
    if (AF32) {
      const float* arow = (const float*)In + (m0 + l15) * (long)LDA + lq * 8;
      float4 p = *(const float4*)(arow + k0);
      float4 q = *(const float4*)(arow + k0 + 4);
      uint4 pk = uint4{packpair(p.x, p.y), packpair(p.z, p.w),
                       packpair(q.x, q.y), packpair(q.z, q.w)};
      af = __builtin_bit_cast(bf16x8, pk);
    } else {
      const u16* arow = (const u16*)In + (m0 + l15) * (long)LDA + lq * 8;
      af = *(const bf16x8*)(arow + k0);
    }
#pragma unroll
    for (int t = 0; t < NT; t++) {
      bf16x8 bfr = *(const bf16x8*)(W + (t * 16 + l15) * K + k0 + lq * 8);
      acc[t] = __builtin_amdgcn_mfma_f32_16x16x32_bf16(af, bfr, acc[t], 0, 0, 0);
    }
  }
#pragma unroll
  for (int t = 0; t < NT; t++) {
    float bv = BIAS ? Bv[t * 16 + l15] : 0.f;
#pragma unroll
    for (int i = 0; i < 4; i++) {
      float v = acc[t][i] + bv;
      if (RELU) v = fmaxf(v, 0.f);
      long off = (m0 + lq * 4 + i) * (long)LDO + t * 16 + l15;
      if (OF32) ((float*)Out)[off] = v;
      else ((u16*)Out)[off] = f2bu(v);
    }
  }
}

// per (bt,h): kvs[m][d] = sum_l khat[l,m]*v[l,d]; ksum[m] = sum_l khat[l,m]
// block id swizzled so the 8 heads of one bt land on one XCD (L2 line sharing)
__global__ __launch_bounds__(256) void spat_stats(const u16* __restrict__ Q,
                                                  float* __restrict__ stats) {
  const int nb = gridDim.x;
  int blk = blockIdx.x;
  const int bh = ((nb & 7) == 0) ? ((blk & 7) * (nb >> 3) + (blk >> 3)) : blk;
  const int bt = bh >> 3, h = bh & 7;
  const int tid = threadIdx.x, lane = tid & 63, wave = tid >> 6;
  float kvs[8][8], ksm[8];
#pragma unroll
  for (int m = 0; m < 8; m++) {
    ksm[m] = 0.f;
#pragma unroll
    for (int d = 0; d < 8; d++) kvs[m][d] = 0.f;
  }
  const u16* base = Q + (long)bt * NN * QC + 64 + h * 8;
  for (int l = tid; l < NN; l += 256) {
    const u16* p = base + (long)l * QC;
    float kv[8], vv[8];
    unpack8(*(const uint4*)p, kv);
    unpack8(*(const uint4*)(p + 64), vv);
    float nr = 0.f;
#pragma unroll
    for (int m = 0; m < 8; m++) nr += kv[m] * kv[m];
    float inv = 1.f / fmaxf(sqrtf(nr), 1e-12f);
#pragma unroll
    for (int m = 0; m < 8; m++) {
      float km = kv[m] * inv;
      ksm[m] += km;
#pragma unroll
      for (int d = 0; d < 8; d++) kvs[m][d] += km * vv[d];
    }
  }
  __shared__ float red[4][72];
#pragma unroll
  for (int m = 0; m < 8; m++) {
    ksm[m] = wredsum(ksm[m]);
#pragma unroll
    for (int d = 0; d < 8; d++) kvs[m][d] = wredsum(kvs[m][d]);
  }
  if (lane == 0) {
#pragma unroll
    for (int m = 0; m < 8; m++) {
      red[wave][64 + m] = ksm[m];
#pragma unroll
      for (int d = 0; d < 8; d++) red[wave][m * 8 + d] = kvs[m][d];
    }
  }
  __syncthreads();
  if (tid < 72) {
    stats[(long)bh * 72 + tid] = red[0][tid] + red[1][tid] + red[2][tid] + red[3][tid];
  }
}

// temporal attention (L=24); writes out_t IN PLACE into k-slot (thread-exclusive slice)
__global__ __launch_bounds__(256) void temp_attn(u16* __restrict__ Q) {
  const long g = (long)blockIdx.x * 256 + threadIdx.x;
  const int h = (int)(g & 7);
  const long bn = g >> 3;
  const int n = (int)(bn & 2047);
  const int b = (int)(bn >> 11);
  u16* qb = Q + ((long)b * TB * NN + n) * QC + h * 8;
  const long ts = (long)NN * QC;
  float kvs[8][8], ksm[8];
#pragma unroll
  for (int m = 0; m < 8; m++) {
    ksm[m] = 0.f;
#pragma unroll
    for (int d = 0; d < 8; d++) kvs[m][d] = 0.f;
  }
  for (int t = 0; t < TB; t++) {
    const u16* p = qb + t * ts;
    float kv[8], vv[8];
    unpack8(*(const uint4*)(p + 64), kv);
    unpack8(*(const uint4*)(p + 128), vv);
    float nr = 0.f;
#pragma unroll
    for (int m = 0; m < 8; m++) nr += kv[m] * kv[m];
    float inv = 1.f / fmaxf(sqrtf(nr), 1e-12f);
#pragma unroll
    for (int m = 0; m < 8; m++) {
      float km = kv[m] * inv;
      ksm[m] += km;
#pragma unroll
      for (int d = 0; d < 8; d++) kvs[m][d] += km * vv[d];
    }
  }
  for (int t = 0; t < TB; t++) {
    u16* p = qb + t * ts;
    float qv[8], vv[8];
    unpack8(*(const uint4*)p, qv);
    unpack8(*(const uint4*)(p + 128), vv);
    float nr = 0.f;
#pragma unroll
    for (int m = 0; m < 8; m++) nr += qv[m] * qv[m];
    float inv = 1.f / fmaxf(sqrtf(nr), 1e-12f);
    float num[8];
    float den = 24.f;
#pragma unroll
    for (int d = 0; d < 8; d++) num[d] = 24.f * vv[d];
#pragma unroll
    for (int m = 0; m < 8; m++) {
      float qm = qv[m] * inv;
      den += qm * ksm[m];
#pragma unroll
      for (int d = 0; d < 8; d++) num[d] += qm * kvs[m][d];
    }
    den = fmaxf(den, 1e-5f);
    float id = 1.f / den;
    uint4 o;
    o.x = packpair(num[0] * id, num[1] * id);
    o.y = packpair(num[2] * id, num[3] * id);
    o.z = packpair(num[4] * id, num[5] * id);
    o.w = packpair(num[6] * id, num[7] * id);
    *(uint4*)(p + 64) = o;
  }
}

// fused temporal + spatial emit: per (b,n,h) thread, loop t: read q,v once,
// write out_s -> q-slot and out_t -> k-slot (thread-exclusive slices)
__global__ __launch_bounds__(256) void temp_spat(u16* __restrict__ Q,
                                                 const float* __restrict__ stats) {
  const long g = (long)blockIdx.x * 256 + threadIdx.x;
  const int h = (int)(g & 7);
  const long bn = g >> 3;
  const int n = (int)(bn & 2047);
  const int b = (int)(bn >> 11);
  u16* qb = Q + ((long)b * TB * NN + n) * QC + h * 8;
  const long ts = (long)NN * QC;
  float kvs[8][8], ksm[8];
#pragma unroll
  for (int m = 0; m < 8; m++) {
    ksm[m] = 0.f;
#pragma unroll
    for (int d = 0; d < 8; d++) kvs[m][d] = 0.f;
  }
  for (int t = 0; t < TB; t++) {
    const u16* p = qb + t * ts;
    float kv[8], vv[8];
    unpack8(*(const uint4*)(p + 64), kv);
    unpack8(*(const uint4*)(p + 128), vv);
    float nr = 0.f;
#pragma unroll
    for (int m = 0; m < 8; m++) nr += kv[m] * kv[m];
    float inv = 1.f / fmaxf(sqrtf(nr), 1e-12f);
#pragma unroll
    for (int m = 0; m < 8; m++) {
      float km = kv[m] * inv;
      ksm[m] += km;
#pragma unroll
      for (int d = 0; d < 8; d++) kvs[m][d] += km * vv[d];
    }
  }
  const float* stb = stats + ((long)b * TB * 8 + h) * 72;
  for (int t = 0; t < TB; t++) {
    u16* p = qb + t * ts;
    const float* st = stb + (long)t * 576;  // ((b*TB+t)*8+h)*72
    float qv[8], vv[8];
    unpack8(*(const uint4*)p, qv);
    unpack8(*(const uint4*)(p + 128), vv);
    float nr = 0.f;
#pragma unroll
    for (int m = 0; m < 8; m++) nr += qv[m] * qv[m];
    float inv = 1.f / fmaxf(sqrtf(nr), 1e-12f);
    float numt[8], nums[8];
    float dent = 24.f, dens = 2048.f;
#pragma unroll
    for (int d = 0; d < 8; d++) {
      numt[d] = 24.f * vv[d];
      nums[d] = 2048.f * vv[d];
    }
#pragma unroll
    for (int m = 0; m < 8; m++) {
      float qm = qv[m] * inv;
      dent += qm * ksm[m];
      dens += qm * st[64 + m];
#pragma unroll
      for (int d = 0; d < 8; d++) {
        numt[d] += qm * kvs[m][d];
        nums[d] += qm * st[m * 8 + d];
      }
    }
    float idt = 1.f / fmaxf(dent, 1e-5f);
    float ids = 1.f / fmaxf(dens, 1e-5f);
    uint4 os, ot;
    os.x = packpair(nums[0] * ids, nums[1] * ids);
    os.y = packpair(nums[2] * ids, nums[3] * ids);
    os.z = packpair(nums[4] * ids, nums[5] * ids);
    os.w = packpair(nums[6] * ids, nums[7] * ids);
    ot.x = packpair(numt[0] * idt, numt[1] * idt);
    ot.y = packpair(numt[2] * idt, numt[3] * idt);
    ot.z = packpair(numt[4] * idt, numt[5] * idt);
    ot.w = packpair(numt[6] * idt, numt[7] * idt);
    *(uint4*)p = os;
    *(uint4*)(p + 64) = ot;
  }
}

// spatial emit; writes out_s IN PLACE into q-slot (thread-exclusive slice)
__global__ __launch_bounds__(256) void spat_out(u16* __restrict__ Q,
                                                const float* __restrict__ stats) {
  const long g = (long)blockIdx.x * 256 + threadIdx.x;
  const int h = (int)(g & 7);
  const long r = g >> 3;
  const int bt = (int)(r >> 11);
  u16* p = Q + r * QC + h * 8;
  float qv[8], vv[8];
  unpack8(*(const uint4*)p, qv);
  unpack8(*(const uint4*)(p + 128), vv);
  const float* st = stats + ((long)bt * 8 + h) * 72;
  float nr = 0.f;
#pragma unroll
  for (int m = 0; m < 8; m++) nr += qv[m] * qv[m];
  float inv = 1.f / fmaxf(sqrtf(nr), 1e-12f);
  const float L = 2048.f;
  float num[8];
#pragma unroll
  for (int d = 0; d < 8; d++) num[d] = L * vv[d];
  float den = L;
#pragma unroll
  for (int m = 0; m < 8; m++) {
    float qm = qv[m] * inv;
    den += qm * st[64 + m];
#pragma unroll
    for (int d = 0; d < 8; d++) num[d] += qm * st[m * 8 + d];
  }
  den = fmaxf(den, 1e-5f);
  float id = 1.f / den;
  uint4 o;
  o.x = packpair(num[0] * id, num[1] * id);
  o.y = packpair(num[2] * id, num[3] * id);
  o.z = packpair(num[4] * id, num[5] * id);
  o.w = packpair(num[6] * id, num[7] * id);
  *(uint4*)p = o;
}

// fused: P1 = att0 @ wp1^T + b; t = 2*(x + att0*P0 + a1*P1*0.01); Y = LN1(t)
// Q rows: [P0 | out_t(dead) | att0]; a1 bf16 row-major 64; x fp32; Y bf16
__global__ __launch_bounds__(256) void pw1_combine_ln(
    const u16* __restrict__ Q, const u16* __restrict__ W,
    const float* __restrict__ Bv, const float* __restrict__ x,
    const u16* __restrict__ a1, const float* __restrict__ g1,
    const float* __restrict__ b1, u16* __restrict__ Y) {
  const int lane = threadIdx.x & 63;
  const int wave = threadIdx.x >> 6;
  const int l15 = lane & 15, lq = lane >> 4;
  const long m0 = ((long)blockIdx.x * 4 + wave) * 16;
  floatx4 acc[4];
#pragma unroll
  for (int t = 0; t < 4; t++) acc[t] = floatx4{0.f, 0.f, 0.f, 0.f};
#pragma unroll
  for (int k0 = 0; k0 < 64; k0 += 32) {
    bf16x8 af = *(const bf16x8*)(Q + (m0 + l15) * 192 + 128 + k0 + lq * 8);
#pragma unroll
    for (int t = 0; t < 4; t++) {
      bf16x8 bfr = *(const bf16x8*)(W + (t * 16 + l15) * 64 + k0 + lq * 8);
      acc[t] = __builtin_amdgcn_mfma_f32_16x16x32_bf16(af, bfr, acc[t], 0, 0, 0);
    }
  }
  float tv[4][4];
#pragma unroll
  for (int t = 0; t < 4; t++) {
    const int col = t * 16 + l15;
    const float bv = Bv[col];
#pragma unroll
    for (int i = 0; i < 4; i++) {
      const long row = m0 + lq * 4 + i;
      float p1v = acc[t][i] + bv;
      float xv = x[row * 64 + col];
      float a0 = b2f(Q[row * 192 + 128 + col]);
      float p0 = b2f(Q[row * 192 + col]);
      float a1v = b2f(a1[row * 64 + col]);
      tv[t][i] = 2.f * (xv + a0 * p0 + a1v * p1v * 0.01f);
    }
  }
#pragma unroll
  for (int i = 0; i < 4; i++) {
    float s = tv[0][i] + tv[1][i] + tv[2][i] + tv[3][i];
    s = red16(s);
    float mu = s * 0.015625f;
    float vs = 0.f;
#pragma unroll
    for (int t = 0; t < 4; t++) {
      float d = tv[t][i] - mu;
      vs += d * d;
    }
    vs = red16(vs);
    float rs = rsqrtf(vs * 0.015625f + 1e-5f);
    const long row = m0 + lq * 4 + i;
#pragma unroll
    for (int t = 0; t < 4; t++) {
      const int col = t * 16 + l15;
      float y = (tv[t][i] - mu) * rs * g1[col] + b1[col];
      Y[row * 64 + col] = f2bu(y);
    }
  }
}

// fused: h2 = Hb @ wf2^T + b; out = LN2(Yb + h2), fp32 out
__global__ __launch_bounds__(256) void fc2_ln(
    const u16* __restrict__ Hb, const u16* __restrict__ W,
    const float* __restrict__ Bv, const u16* __restrict__ Yb,
    const float* __restrict__ g2, const float* __restrict__ b2v,
    float* __restrict__ out) {
  const int lane = threadIdx.x & 63;
  const int wave = threadIdx.x >> 6;
  const int l15 = lane & 15, lq = lane >> 4;
  const long m0 = ((long)blockIdx.x * 4 + wave) * 16;
  floatx4 acc[4];
#pragma unroll
  for (int t = 0; t < 4; t++) acc[t] = floatx4{0.f, 0.f, 0.f, 0.f};
#pragma unroll
  for (int k0 = 0; k0 < 128; k0 += 32) {
    bf16x8 af = *(const bf16x8*)(Hb + (m0 + l15) * 128 + k0 + lq * 8);
#pragma unroll
    for (int t = 0; t < 4; t++) {
      bf16x8 bfr = *(const bf16x8*)(W + (t * 16 + l15) * 128 + k0 + lq * 8);
      acc[t] = __builtin_amdgcn_mfma_f32_16x16x32_bf16(af, bfr, acc[t], 0, 0, 0);
    }
  }
  float tv[4][4];
#pragma unroll
  for (int t = 0; t < 4; t++) {
    const int col = t * 16 + l15;
    const float bv = Bv[col];
#pragma unroll
    for (int i = 0; i < 4; i++) {
      const long row = m0 + lq * 4 + i;
      tv[t][i] = acc[t][i] + bv + b2f(Yb[row * 64 + col]);
    }
  }
#pragma unroll
  for (int i = 0; i < 4; i++) {
    float s = tv[0][i] + tv[1][i] + tv[2][i] + tv[3][i];
    s = red16(s);
    float mu = s * 0.015625f;
    float vs = 0.f;
#pragma unroll
    for (int t = 0; t < 4; t++) {
      float d = tv[t][i] - mu;
      vs += d * d;
    }
    vs = red16(vs);
    float rs = rsqrtf(vs * 0.015625f + 1e-5f);
    const long row = m0 + lq * 4 + i;
#pragma unroll
    for (int t = 0; t < 4; t++) {
      const int col = t * 16 + l15;
      out[row * 64 + col] = (tv[t][i] - mu) * rs * g2[col] + b2v[col];
    }
  }
}

// y = LN(2*(x + att0*p0 + att1*p1*0.01)); x fp32, att1 fp32, rest bf16; wave/row
__global__ __launch_bounds__(256) void combine_ln(
    const float* __restrict__ x, const u16* __restrict__ a0p, int sa0,
    const float* __restrict__ a1p, const u16* __restrict__ P0, int sp0,
    const u16* __restrict__ P1, int sp1, const float* __restrict__ g1,
    const float* __restrict__ b1, u16* __restrict__ Y) {
  const long r = (long)blockIdx.x * 4 + (threadIdx.x >> 6);
  const int d = threadIdx.x & 63;
  float xv = x[r * 64 + d];
  float a0 = b2f(a0p[r * sa0 + d]);
  float a1 = a1p[r * 64 + d];
  float p0 = b2f(P0[r * sp0 + d]);
  float p1 = b2f(P1[r * sp1 + d]);
  float t = 2.f * (xv + a0 * p0 + a1 * p1 * 0.01f);
  float mu = wredsum(t) * 0.015625f;
  float dv = t - mu;
  float var = wredsum(dv * dv) * 0.015625f;
  float y = dv * rsqrtf(var + 1e-5f) * g1[d] + b1[d];
  Y[r * 64 + d] = f2bu(y);
}

// out = LN(y + ffn); bf16 ins, fp32 out
__global__ __launch_bounds__(256) void final_ln(const u16* __restrict__ Yp,
                                                const u16* __restrict__ Op,
                                                const float* __restrict__ g2,
                                                const float* __restrict__ b2p,
                                                float* __restrict__ out) {
  const long r = (long)blockIdx.x * 4 + (threadIdx.x >> 6);
  const int d = threadIdx.x & 63;
  const long o = r * 64 + d;
  float t = b2f(Yp[o]) + b2f(Op[o]);
  float mu = wredsum(t) * 0.015625f;
  float dv = t - mu;
  float var = wredsum(dv * dv) * 0.015625f;
  out[o] = dv * rsqrtf(var + 1e-5f) * g2[d] + b2p[d];
}

extern "C" void kernel_launch(void* const* d_in, const int* in_sizes, int n_in,
                              void* d_out, int out_size, void* d_ws, size_t ws_size,
                              hipStream_t stream) {
  const float* x = (const float*)d_in[0];
  const float* phi = (const float*)d_in[1];
  const float* phiinv = (const float*)d_in[2];
  const float* diagw = (const float*)d_in[3];
  const float* qkv0w = (const float*)d_in[4];
  const float* out0w = (const float*)d_in[5];
  const float* out0b = (const float*)d_in[6];
  const float* qkv1w = (const float*)d_in[7];
  const float* out1w = (const float*)d_in[8];
  const float* out1b = (const float*)d_in[9];
  const float* pw0w = (const float*)d_in[10];
  const float* pw0b = (const float*)d_in[11];
  const float* pw1w = (const float*)d_in[12];
  const float* pw1b = (const float*)d_in[13];
  const float* fc1w = (const float*)d_in[14];
  const float* fc1b = (const float*)d_in[15];
  const float* fc2w = (const float*)d_in[16];
  const float* fc2b = (const float*)d_in[17];
  const float* ln1g = (const float*)d_in[18];
  const float* ln1b = (const float*)d_in[19];
  const float* ln2g = (const float*)d_in[20];
  const float* ln2b = (const float*)d_in[21];

  const long per = 25221120L;
  int CH = 1;
  if ((long)ws_size >= 262144L + 8 * per) CH = 8;
  else if ((long)ws_size >= 262144L + 4 * per) CH = 4;
  else if ((long)ws_size >= 262144L + 2 * per) CH = 2;
  const int NCH = 8 / CH;

  char* ws = (char*)d_ws;
  u16* wb = (u16*)ws;  // bf16 weights: q0,q1,o0,o1,p0,p1,f1,f2
  u16* wq0 = wb + 0;
  u16* wq1 = wb + 12288;
  u16* wo0 = wb + 24576;
  u16* wo1 = wb + 32768;
  u16* wp0 = wb + 40960;
  u16* wp1 = wb + 45056;
  u16* wf1 = wb + 49152;
  u16* wf2 = wb + 57344;
  const long B0 = 262144L;
  float* dof = (float*)d_out;

  // stage 0: all weights -> bf16, one dispatch
  cast_weights<<<256, 256, 0, stream>>>(qkv0w, qkv1w, out0w, out1w, pw0w, pw1w,
                                        fc1w, fc2w, wb);

  if (CH == 8) {
    // ---- new fused pipeline (ws >= B0 + 201,768,960, same peak as before) ----
    // phase A layout (sequential lifetimes, all within [B0, B0+201.8MB)):
    //   PT  [0,   33.5M)   dead after split-K gemm
    //   PB  [33.5,67.1M)   dead after split-K gemm
    //   MsP [67.1,134.2M)  fp32 partials, dead after reduce_ms
    //   Ms  [134.2,142.6M) dead after xk gemm
    //   XT  [0,   50.3M)   written by prep_xt (PT/PB dead), dead after xk gemm
    //   XB  [151.4,201.8M) bf16 row-major x, lives through phase C (== Yb slot)
    // d_out doubles as bf16 scratch: xkb [0,50.3M), a1b [50.3,100.6M)
    u16* PT = (u16*)(ws + B0);
    u16* PB = (u16*)(ws + B0 + 33554432L);
    float* MsP = (float*)(ws + B0 + 67108864L);
    u16* Ms = (u16*)(ws + B0 + 134217728L);
    u16* XT = (u16*)(ws + B0);
    u16* XB = (u16*)(ws + B0 + 151437312L);
    u16* Q = (u16*)(ws + B0);                      // 150,994,944
    float* st = (float*)(ws + B0 + 150994944L);    // 442,368
    u16* Yb = XB;                                  // reuse (XB dead after p0)
    u16* Hb = (u16*)(ws + B0);                     // Q dead after pw1_combine_ln
    u16* xkb = (u16*)d_out;
    u16* a1b = xkb + 25165824L;

    // phase A: Msum via split-K (4 blocks/CU instead of 1), then xk -> bf16
    prep_pt<<<dim3(32, 32, 4), 256, 0, stream>>>(phiinv, diagw, PT);
    cast_bulk<<<8192, 256, 0, stream>>>(phi, PB);
    gemm128<2><<<dim3(16, 16, 4), 256, 0, stream>>>(PB, PT, MsP, 2048, 2048, 2048,
                                                    2048, 1, 4194304L, 4194304L);
    reduce_ms<<<2048, 256, 0, stream>>>(MsP, Ms);
    prep_xt<<<dim3(32, 192), 256, 0, stream>>>(x, XT, XB);
    gemm128<3><<<dim3(16, 96), 256, 0, stream>>>(Ms, XT, xkb, 2048, 2048, 2048, 0,
                                                 1, 0L, 0L);
    // phase B: attention layer 1 (xk bf16 -> att1 bf16 in d_out upper half)
    skinny_gemm<64, 64, 192, 192, false, false, false, false>
        <<<6144, 256, 0, stream>>>(xkb, wq1, nullptr, Q);
    spat_stats<<<1536, 256, 0, stream>>>(Q, st);
    temp_spat<<<512, 256, 0, stream>>>(Q, st);
    skinny_gemm<128, 192, 64, 64, true, false, false, false>
        <<<6144, 256, 0, stream>>>(Q, wo1, out1b, a1b);
    // phase C: attention layer 0 + gating + LN1 + FFN + LN2 (fused epilogues)
    skinny_gemm<64, 64, 192, 192, false, false, false, false>
        <<<6144, 256, 0, stream>>>(XB, wq0, nullptr, Q);
    spat_stats<<<1536, 256, 0, stream>>>(Q, st);
    temp_spat<<<512, 256, 0, stream>>>(Q, st);
    // att0 -> v-slot (reads cols 0:128 of own rows, writes 128:192 -- disjoint)
    skinny_gemm<128, 192, 64, 192, true, false, false, false>
        <<<6144, 256, 0, stream>>>(Q, wo0, out0b, Q + 128);
    // P0 -> q-slot (out_s consumed by out0 above)
    skinny_gemm<64, 64, 64, 192, true, false, false, false>
        <<<6144, 256, 0, stream>>>(XB, wp0, pw0b, Q);
    // P1-gemm + combine + LN1 fused (kills P1 round-trip); writes Yb over XB
    pw1_combine_ln<<<6144, 256, 0, stream>>>(Q, wp1, pw1b, x, a1b, ln1g, ln1b, Yb);
    skinny_gemm<64, 64, 128, 128, true, true, false, false>
        <<<6144, 256, 0, stream>>>(Yb, wf1, fc1b, Hb);
    // fc2 + residual + LN2 fused, fp32 out (kills Ob round-trip)
    fc2_ln<<<6144, 256, 0, stream>>>(Hb, wf2, fc2b, Yb, ln2g, ln2b, dof);
  } else {
    // ---- legacy small-ws fallback (unchanged) ----
    u16* Ms = (u16*)(ws + B0);
    u16* PT = (u16*)(ws + B0 + 8388608L);
    u16* XT = (u16*)(ws + B0 + 8388608L);
    u16* Q = (u16*)(ws + B0);
    float* st = (float*)(ws + B0 + (long)CH * 18874368L);
    u16* Yb = (u16*)(ws + B0 + (long)CH * 18929664L);
    u16* Hb = (u16*)(ws + B0);
    u16* Ob = (u16*)(ws + B0 + (long)CH * 12582912L);

    for (int s = 0; s < 4; s++) {
      prep_pt<<<dim3(32, 32, 1), 256, 0, stream>>>(phiinv + (long)s * 4194304,
                                                   diagw + (long)s * 2048, PT);
      gemm_bt<true, false><<<dim3(32, 32, 1), 256, 0, stream>>>(
          phi + (long)s * 4194304, PT, Ms, 2048, 2048, 2048, 2048, 1, 0L, 0L, 0L,
          0L, s ? 1 : 0);
    }
    for (int c = 0; c < NCH; c++) {
      long eoff = (long)c * CH * 49152 * 64;
      prep_xt<<<dim3(32, CH * 24), 256, 0, stream>>>(x + eoff, XT, nullptr);
      gemm_bt<false, true><<<dim3(32, 1, CH * 24), 256, 0, stream>>>(
          Ms, XT, dof + eoff, 2048, 2048, 2048, 64, 1, 0L, 0L, 131072L, 131072L, 0);
    }
    for (int c = 0; c < NCH; c++) {
      long eoff = (long)c * CH * 49152 * 64;
      skinny_gemm<64, 64, 192, 192, false, false, true, false>
          <<<CH * 768, 256, 0, stream>>>(dof + eoff, wq1, nullptr, Q);
      spat_stats<<<CH * 192, 256, 0, stream>>>(Q, st);
      temp_attn<<<CH * 64, 256, 0, stream>>>(Q);
      spat_out<<<CH * 1536, 256, 0, stream>>>(Q, st);
      skinny_gemm<128, 192, 64, 64, true, false, false, true>
          <<<CH * 768, 256, 0, stream>>>(Q, wo1, out1b, dof + eoff);
    }
    for (int c = 0; c < NCH; c++) {
      long eoff = (long)c * CH * 49152 * 64;
      const float* x_c = x + eoff;
      skinny_gemm<64, 64, 192, 192, false, false, true, false>
          <<<CH * 768, 256, 0, stream>>>(x_c, wq0, nullptr, Q);
      spat_stats<<<CH * 192, 256, 0, stream>>>(Q, st);
      temp_attn<<<CH * 64, 256, 0, stream>>>(Q);
      spat_out<<<CH * 1536, 256, 0, stream>>>(Q, st);
      skinny_gemm<128, 192, 64, 192, true, false, false, false>
          <<<CH * 768, 256, 0, stream>>>(Q, wo0, out0b, Q + 128);
      skinny_gemm<64, 64, 64, 192, true, false, true, false>
          <<<CH * 768, 256, 0, stream>>>(x_c, wp0, pw0b, Q);
      skinny_gemm<64, 192, 64, 192, true, false, false, false>
          <<<CH * 768, 256, 0, stream>>>(Q + 128, wp1, pw1b, Q + 64);
      combine_ln<<<CH * 12288, 256, 0, stream>>>(x_c, Q + 128, 192, dof + eoff, Q,
                                                 192, Q + 64, 192, ln1g, ln1b, Yb);
      skinny_gemm<64, 64, 128, 128, true, true, false, false>
          <<<CH * 768, 256, 0, stream>>>(Yb, wf1, fc1b, Hb);
      skinny_gemm<128, 128, 64, 64, true, false, false, false>
          <<<CH * 768, 256, 0, stream>>>(Hb, wf2, fc2b, Ob);
      final_ln<<<CH * 12288, 256, 0, stream>>>(Yb, Ob, ln2g, ln2b, dof + eoff);
    }
  }
}